// Round 8
// baseline (238.829 us; speedup 1.0000x reference)
//
#include <hip/hip_runtime.h>
#include <math.h>

#define EPSF 1e-8f
#define LAM 20.0f

typedef short short8 __attribute__((ext_vector_type(8)));
typedef float f32x4 __attribute__((ext_vector_type(4)));

__device__ __forceinline__ unsigned short f2bf(float x) {
  unsigned u = __float_as_uint(x);
  u += 0x7fffu + ((u >> 16) & 1u);
  return (unsigned short)(u >> 16);
}
__device__ __forceinline__ float bf2f(unsigned short h) {
  return __uint_as_float(((unsigned)h) << 16);
}
// async global->LDS 16B: dest = wave-uniform lds base + lane*16
__device__ __forceinline__ void gload_lds16(const void* g, void* l) {
  __builtin_amdgcn_global_load_lds(
      (const __attribute__((address_space(1))) unsigned int*)g,
      (__attribute__((address_space(3))) unsigned int*)l, 16, 0, 0);
}

// ---------------------------------------------------------------------------
// Kernel 1 (fused): row norms + normalized bf16 copies + bf16 Gram via MFMA.
// Blocks 0..127: images (LS=64). Blocks 128..255: captions (LS=32).
// ---------------------------------------------------------------------------
template <int LS>
__device__ __forceinline__ void gram_norm_body(
    const float* __restrict__ raw, float* __restrict__ nrm,
    unsigned short* __restrict__ nbf, unsigned short* __restrict__ Gbf,
    int c, char* sm, float* cinv) {
  constexpr int RW = (LS == 64) ? 2 : 1;
  const int t = threadIdx.x;
  const int w = t >> 6, lane = t & 63, m16 = lane & 15, grp = lane >> 4;
  const float* base = raw + ((size_t)c * LS << 9);

  // pass 0: row norms (one wave per row, LS/4 rounds)
  for (int r = w; r < LS; r += 4) {
    const float* rp = base + ((size_t)r << 9);
    float ss = 0.f;
#pragma unroll
    for (int i = 0; i < 8; i++) {
      float v = rp[lane + (i << 6)];
      ss = fmaf(v, v, ss);
    }
#pragma unroll
    for (int o = 32; o; o >>= 1) ss += __shfl_xor(ss, o);
    if (lane == 0) {
      float n = sqrtf(ss);
      nrm[c * LS + r] = n;
      cinv[r] = 1.0f / (n + EPSF);
    }
  }
  __syncthreads();

  // pass 1: per K-128 chunk: normalize->bf16 (LDS + global), MFMA gram
  const int rT0 = (w & 1) * RW, cT0 = (w >> 1) * RW;
  f32x4 g[RW][RW];
#pragma unroll
  for (int ri = 0; ri < RW; ri++)
#pragma unroll
    for (int ci = 0; ci < RW; ci++) g[ri][ci] = {0.f, 0.f, 0.f, 0.f};

  for (int ch = 0; ch < 4; ch++) {
    __syncthreads();
    for (int idx = t; idx < LS * 16; idx += 256) {
      int row = idx >> 4, u = idx & 15;
      const float* sp = base + ((size_t)row << 9) + (ch << 7) + u * 8;
      float4 aa = *(const float4*)sp;
      float4 bb = *(const float4*)(sp + 4);
      float ci = cinv[row];
      union { unsigned short us[8]; uint4 v; } p;
      p.us[0] = f2bf(aa.x * ci); p.us[1] = f2bf(aa.y * ci);
      p.us[2] = f2bf(aa.z * ci); p.us[3] = f2bf(aa.w * ci);
      p.us[4] = f2bf(bb.x * ci); p.us[5] = f2bf(bb.y * ci);
      p.us[6] = f2bf(bb.z * ci); p.us[7] = f2bf(bb.w * ci);
      *(uint4*)(sm + row * 272 + u * 16) = p.v;
      ((uint4*)(nbf + (((size_t)(c * LS + row)) << 9) + (ch << 7)))[u] = p.v;
    }
    __syncthreads();
#pragma unroll
    for (int kk = 0; kk < 4; kk++) {
      short8 a[RW], b[RW];
#pragma unroll
      for (int ri = 0; ri < RW; ri++)
        a[ri] = *(const short8*)(sm + ((rT0 + ri) * 16 + m16) * 272 + kk * 64 + grp * 16);
#pragma unroll
      for (int ci = 0; ci < RW; ci++)
        b[ci] = *(const short8*)(sm + ((cT0 + ci) * 16 + m16) * 272 + kk * 64 + grp * 16);
#pragma unroll
      for (int ri = 0; ri < RW; ri++)
#pragma unroll
        for (int ci = 0; ci < RW; ci++)
          g[ri][ci] = __builtin_amdgcn_mfma_f32_16x16x32_bf16(a[ri], b[ci], g[ri][ci], 0, 0, 0);
    }
  }
#pragma unroll
  for (int ri = 0; ri < RW; ri++)
#pragma unroll
    for (int ci = 0; ci < RW; ci++)
#pragma unroll
      for (int r = 0; r < 4; r++) {
        int s = (rT0 + ri) * 16 + grp * 4 + r;
        int sp = (cT0 + ci) * 16 + m16;
        Gbf[(size_t)c * LS * LS + s * LS + sp] = f2bf(g[ri][ci][r]);
      }
}

__global__ __launch_bounds__(256, 2) void gram_norm(
    const float* __restrict__ im, const float* __restrict__ s,
    float* __restrict__ nim, float* __restrict__ ns,
    unsigned short* __restrict__ imn, unsigned short* __restrict__ sn,
    unsigned short* __restrict__ Gim, unsigned short* __restrict__ Gs) {
  __shared__ __align__(16) char sm[64 * 272 + 64 * 4];
  float* cinv = (float*)(sm + 64 * 272);
  if (blockIdx.x < 128)
    gram_norm_body<64>(im, nim, imn, Gim, blockIdx.x, sm, cinv);
  else
    gram_norm_body<32>(s, ns, sn, Gs, blockIdx.x - 128, sm, cinv);
}

// ---------------------------------------------------------------------------
// Kernel 2: macro-tiled fused attention (R7 structure + global_load_lds
// staging with XOR-swizzled pitch-128 rows; i2t fits 4 blocks/CU).
// ---------------------------------------------------------------------------
template <int LS, int LQ, int GC, int GQ, int MINW>
__global__ __launch_bounds__(256, MINW) void attn_tile(
    const unsigned short* __restrict__ ctxn,  // (128,LS,512) bf16
    const unsigned short* __restrict__ qryn,  // (128,LQ,512) bf16
    const unsigned short* __restrict__ Gbf,   // (128,LS,LS) bf16
    const float* __restrict__ qnrm,           // 128*LQ raw query norms
    const float* __restrict__ cmask,          // (128,LS)
    float* __restrict__ sim) {
  static_assert(GC * LS == 128 && GQ * LQ == 128, "tile must be 128x128");
  constexpr int S0P = 264;                  // S0/e row pitch (bytes)
  constexpr int FOFF = 127 * S0P + 256;     // 33784: union(staging 32768, S0)
  constexpr int WPC = 4 / GC;               // waves per context in P3
  constexpr int KS3 = LS / 32;              // P3 k-steps: 2 (i2t) / 1 (t2i)
  constexpr int NF = GQ * 128 + 2 * GC * 128 + 512 + 256 + GC;
  static_assert(256 * 128 <= FOFF, "staging overflows union");
  __shared__ __align__(16) char sm[FOFF + NF * 4];
  float* rinvv = (float*)(sm + FOFF);       // [GQ][128]
  float* sumev = rinvv + GQ * 128;          // [GC][128]  sum e*v
  float* invv = sumev + GC * 128;           // [GC][128]  1/sum e
  float* psum = invv + GC * 128;            // [4][128] wn2 wave partials
  float* cmv = psum + 512;                  // [128]
  float* qnv = cmv + 128;                   // [128]
  float* cmmaxv = qnv + 128;                // [GC]

  const int bq = blockIdx.x, bc = blockIdx.y, t = threadIdx.x;
  const int w = t >> 6, lane = t & 63, m16 = lane & 15, grp = lane >> 4;

  auto soff = [](int n) { return n * S0P; };

  const unsigned short* aBase = ctxn + ((size_t)bc << 16);  // bc*128*512
  const unsigned short* bBase = qryn + ((size_t)bq << 16);

  // ---- preload cmask, qnorms; G fragments -> registers ----
  if (t < 128) cmv[t] = cmask[bc * 128 + t];
  else qnv[t - 128] = qnrm[bq * 128 + (t - 128)];
  const int c3 = w / WPC, hf = w % WPC;
  short8 g_a[2][KS3];
  {
    const unsigned short* gB = Gbf + (size_t)bc * GC * LS * LS + c3 * LS * LS;
#pragma unroll
    for (int mi = 0; mi < 2; mi++) {
      int sp = (hf * 2 + mi) * 16 + m16;
#pragma unroll
      for (int ks = 0; ks < KS3; ks++)
        g_a[mi][ks] = *(const short8*)(gB + sp * LS + ks * 32 + grp * 8);
    }
  }

  // shared accumulator file: P1 uses regs[si*4+ni], P3 uses regs[mi*8+nt]
  f32x4 regs[16];
#pragma unroll
  for (int i = 0; i < 16; i++) regs[i] = {0.f, 0.f, 0.f, 0.f};

  // ---- Phase 1: 128x128x512 score GEMM; async staging, swizzled slots ----
  // LDS slot (row, s) holds global 16B-chunk u = s ^ (row&7); rows pitch 128.
  const int sT0 = (w & 1) * 4, nT0 = (w >> 1) * 4;
  const int srow = lane >> 3, sswz = lane & 7;
  for (int ch = 0; ch < 8; ch++) {
    __syncthreads();  // prior MFMA reads done
#pragma unroll
    for (int i = 0; i < 8; i++) {
      int rb = (i * 4 + w) * 8;  // wave-uniform 8-row block
      int row = rb + srow;
      int u = sswz ^ (row & 7);
      const unsigned short* src =
          (row < 128) ? (aBase + ((size_t)row << 9)) : (bBase + ((size_t)(row - 128) << 9));
      gload_lds16(src + ch * 64 + u * 8, sm + rb * 128);
    }
    __syncthreads();  // drains vmcnt -> staging ready
#pragma unroll
    for (int kk = 0; kk < 2; kk++) {
      short8 av[4], bv[4];
#pragma unroll
      for (int si = 0; si < 4; si++) {
        int rA = (sT0 + si) * 16 + m16;
        av[si] = *(const short8*)(sm + rA * 128 + (((kk * 4 + grp) ^ (rA & 7)) << 4));
      }
#pragma unroll
      for (int ni = 0; ni < 4; ni++) {
        int rB = 128 + (nT0 + ni) * 16 + m16;
        bv[ni] = *(const short8*)(sm + rB * 128 + (((kk * 4 + grp) ^ (rB & 7)) << 4));
      }
#pragma unroll
      for (int si = 0; si < 4; si++)
#pragma unroll
        for (int ni = 0; ni < 4; ni++)
          regs[si * 4 + ni] = __builtin_amdgcn_mfma_f32_16x16x32_bf16(
              av[si], bv[ni], regs[si * 4 + ni], 0, 0, 0);
    }
  }
  __syncthreads();
  // write S0 bf16 [n][m]; C-layout rows (grp*4+r) are consecutive m -> 8B store
#pragma unroll
  for (int si = 0; si < 4; si++)
#pragma unroll
    for (int ni = 0; ni < 4; ni++) {
      int n = (nT0 + ni) * 16 + m16;
      int m0 = (sT0 + si) * 16 + grp * 4;
      f32x4 a = regs[si * 4 + ni];
      ushort4 p;
      p.x = f2bf(a[0]); p.y = f2bf(a[1]);
      p.z = f2bf(a[2]); p.w = f2bf(a[3]);
      *(ushort4*)(sm + soff(n) + m0 * 2) = p;
    }
  __syncthreads();

  // ---- Phase 2a: rinv (vectorized b64) + per-ci cmask max ----
  {
    if (t < GQ * 32) {
      int qi = t >> 5, mg = (t & 31) * 4;
      float s0 = 0.f, s1 = 0.f, s2 = 0.f, s3 = 0.f;
      for (int l = 0; l < LQ; l++) {
        uint2 pk = *(const uint2*)(sm + soff(qi * LQ + l) + mg * 2);
        float v0 = __uint_as_float(pk.x << 16);
        float v1 = __uint_as_float(pk.x & 0xffff0000u);
        float v2 = __uint_as_float(pk.y << 16);
        float v3 = __uint_as_float(pk.y & 0xffff0000u);
        v0 = v0 > 0.f ? v0 : 0.1f * v0;
        v1 = v1 > 0.f ? v1 : 0.1f * v1;
        v2 = v2 > 0.f ? v2 : 0.1f * v2;
        v3 = v3 > 0.f ? v3 : 0.1f * v3;
        s0 = fmaf(v0, v0, s0); s1 = fmaf(v1, v1, s1);
        s2 = fmaf(v2, v2, s2); s3 = fmaf(v3, v3, s3);
      }
      rinvv[qi * 128 + mg + 0] = 1.0f / (sqrtf(s0) + EPSF);
      rinvv[qi * 128 + mg + 1] = 1.0f / (sqrtf(s1) + EPSF);
      rinvv[qi * 128 + mg + 2] = 1.0f / (sqrtf(s2) + EPSF);
      rinvv[qi * 128 + mg + 3] = 1.0f / (sqrtf(s3) + EPSF);
    } else if (t < GQ * 32 + GC) {
      int ci = t - GQ * 32;
      float mx = cmv[ci * LS];
      for (int s = 1; s < LS; s++) mx = fmaxf(mx, cmv[ci * LS + s]);
      cmmaxv[ci] = mx;
    }
  }
  __syncthreads();

  // ---- Phase 2b: ONE-pass softmax (analytic max); store unnormalized e ----
  {
    const int n = t & 127;
    const int qi = n / LQ;
    for (int ci = t >> 7; ci < GC; ci += 2) {
      char* rowp = sm + soff(n) + ci * LS * 2;
      const float* rv = rinvv + qi * 128 + ci * LS;
      const float* cv = cmv + ci * LS;
      const float mxc = LAM * (1.0f + cmmaxv[ci]);
      float sum = 0.f, sev = 0.f;
#pragma unroll
      for (int u = 0; u < LS / 4; u++) {
        uint2 pk = *(const uint2*)(rowp + u * 8);
        float v0 = __uint_as_float(pk.x << 16);
        float v1 = __uint_as_float(pk.x & 0xffff0000u);
        float v2 = __uint_as_float(pk.y << 16);
        float v3 = __uint_as_float(pk.y & 0xffff0000u);
        int s = u * 4;
        float l0 = v0 > 0.f ? v0 : 0.1f * v0;
        float l1 = v1 > 0.f ? v1 : 0.1f * v1;
        float l2 = v2 > 0.f ? v2 : 0.1f * v2;
        float l3 = v3 > 0.f ? v3 : 0.1f * v3;
        float e0 = __expf(LAM * fmaf(l0, rv[s + 0], cv[s + 0]) - mxc);
        float e1 = __expf(LAM * fmaf(l1, rv[s + 1], cv[s + 1]) - mxc);
        float e2 = __expf(LAM * fmaf(l2, rv[s + 2], cv[s + 2]) - mxc);
        float e3 = __expf(LAM * fmaf(l3, rv[s + 3], cv[s + 3]) - mxc);
        sum += (e0 + e1) + (e2 + e3);
        sev = fmaf(e0, v0, sev); sev = fmaf(e1, v1, sev);
        sev = fmaf(e2, v2, sev); sev = fmaf(e3, v3, sev);
        uint2 o;
        o.x = (unsigned)f2bf(e0) | ((unsigned)f2bf(e1) << 16);
        o.y = (unsigned)f2bf(e2) | ((unsigned)f2bf(e3) << 16);
        *(uint2*)(rowp + u * 8) = o;
      }
      sumev[ci * 128 + n] = sev;
      invv[ci * 128 + n] = 1.0f / sum;
    }
  }
  __syncthreads();

  // ---- Phase 3: per-c U = G_c @ e_c (MFMA, A from regs); wn2 from C-regs ----
  {
#pragma unroll
    for (int i = 0; i < 16; i++) regs[i] = {0.f, 0.f, 0.f, 0.f};
#pragma unroll
    for (int ks = 0; ks < KS3; ks++) {
      short8 b2[8];
#pragma unroll
      for (int nt = 0; nt < 8; nt++) {
        const char* p = sm + soff(nt * 16 + m16) + c3 * LS * 2 + ks * 64 + grp * 16;
        union { uint2 h[2]; short8 v; } bb;
        bb.h[0] = *(const uint2*)(p);
        bb.h[1] = *(const uint2*)(p + 8);
        b2[nt] = bb.v;
      }
#pragma unroll
      for (int mi = 0; mi < 2; mi++)
#pragma unroll
        for (int nt = 0; nt < 8; nt++)
          regs[mi * 8 + nt] = __builtin_amdgcn_mfma_f32_16x16x32_bf16(
              g_a[mi][ks], b2[nt], regs[mi * 8 + nt], 0, 0, 0);
    }
    float wp[8];
#pragma unroll
    for (int nt = 0; nt < 8; nt++) wp[nt] = 0.f;
#pragma unroll
    for (int nt = 0; nt < 8; nt++) {
#pragma unroll
      for (int mi = 0; mi < 2; mi++) {
        int sp = (hf * 2 + mi) * 16 + grp * 4;
        uint2 ee = *(const uint2*)(sm + soff(nt * 16 + m16) + (c3 * LS + sp) * 2);
        f32x4 uu = regs[mi * 8 + nt];
        wp[nt] += __uint_as_float(ee.x << 16) * uu[0] +
                  __uint_as_float(ee.x & 0xffff0000u) * uu[1] +
                  __uint_as_float(ee.y << 16) * uu[2] +
                  __uint_as_float(ee.y & 0xffff0000u) * uu[3];
      }
    }
#pragma unroll
    for (int o = 16; o < 64; o <<= 1)
#pragma unroll
      for (int nt = 0; nt < 8; nt++) wp[nt] += __shfl_xor(wp[nt], o);
    if (lane < 16) {
#pragma unroll
      for (int nt = 0; nt < 8; nt++) psum[w * 128 + nt * 16 + lane] = wp[nt];
    }
  }
  __syncthreads();

  // ---- Final: cos + mean over l -> sim ----
  {
    const int p = t >> 5, l0 = t & 31;
    const int cc = p / GQ, qi = p % GQ;
    float sum = 0.f;
#pragma unroll
    for (int li = 0; li < LQ / 32; li++) {
      int n = qi * LQ + l0 + li * 32;
      float nq = qnv[n];
      float inv = invv[cc * 128 + n];
      float w12 = sumev[cc * 128 + n] * inv;
      float wn2u = 0.f;
#pragma unroll
      for (int h = 0; h < WPC; h++) wn2u += psum[(cc * WPC + h) * 128 + n];
      float wn2 = wn2u * inv * inv;
      float denom = fmaxf(nq * sqrtf(fmaxf(wn2, 0.f)), 1e-8f);
      sum += (nq + EPSF) * w12 / denom;
    }
#pragma unroll
    for (int o = 1; o < 32; o <<= 1) sum += __shfl_xor(sum, o);
    if (l0 == 0) sim[(bc * GC + cc) * 128 + bq * GQ + qi] = sum * (1.0f / (float)LQ);
  }
}

// ---------------------------------------------------------------------------
// Loss reductions (unchanged, exact).
// ---------------------------------------------------------------------------
__global__ __launch_bounds__(128) void loss_rows(
    const float* __restrict__ gsim, const float* __restrict__ i2t,
    const float* __restrict__ t2i, float* __restrict__ grow,
    float* __restrict__ gcol, float* __restrict__ lrow) {
  const int i = blockIdx.x, j = threadIdx.x;
  const int B = 128;
  __shared__ float sh[2];
  auto bmax = [&](float v) -> float {
#pragma unroll
    for (int o = 32; o; o >>= 1) v = fmaxf(v, __shfl_down(v, o));
    if ((j & 63) == 0) sh[j >> 6] = v;
    __syncthreads();
    float r = fmaxf(sh[0], sh[1]);
    __syncthreads();
    return r;
  };
  auto bsum = [&](float v) -> float {
#pragma unroll
    for (int o = 32; o; o >>= 1) v += __shfl_down(v, o);
    if ((j & 63) == 0) sh[j >> 6] = v;
    __syncthreads();
    float r = sh[0] + sh[1];
    __syncthreads();
    return r;
  };
  float xr = gsim[i * B + j] * 20.f;
  float xc = gsim[j * B + i] * 20.f;
  float sc = (i2t[i * B + j] + t2i[j * B + i]) * LAM;
  float mr = bmax(xr);
  float lser = mr + logf(bsum(__expf(xr - mr)));
  float mc = bmax(xc);
  float lsec = mc + logf(bsum(__expf(xc - mc)));
  float ml = bmax(sc);
  float lsel = ml + logf(bsum(__expf(sc - ml)));
  float pred = __expf(sc - lsel);
  float logLab = (i == j) ? logf(1.0f + 1e-6f) : logf(1e-6f);
  float tsum = bsum(pred * (sc - lsel - logLab));
  if (j == 0) {
    float d = gsim[i * B + i] * 20.f;
    grow[i] = d - lser;
    gcol[i] = d - lsec;
    lrow[i] = tsum;
  }
}

__global__ __launch_bounds__(128) void loss_final(const float* __restrict__ grow,
                                                  const float* __restrict__ gcol,
                                                  const float* __restrict__ lrow,
                                                  float* __restrict__ out) {
  const int j = threadIdx.x;
  __shared__ float sh[2];
  auto bsum = [&](float v) -> float {
#pragma unroll
    for (int o = 32; o; o >>= 1) v += __shfl_down(v, o);
    if ((j & 63) == 0) sh[j >> 6] = v;
    __syncthreads();
    float r = sh[0] + sh[1];
    __syncthreads();
    return r;
  };
  float a = bsum(grow[j]);
  float b = bsum(gcol[j]);
  float c = bsum(lrow[j]);
  if (j == 0) {
    float gl = -(a / 128.f) - (b / 128.f);
    float ll = c / 128.f;
    out[0] = gl + ll;
    out[1] = gl;
    out[2] = ll;
  }
}

extern "C" void kernel_launch(void* const* d_in, const int* in_sizes, int n_in,
                              void* d_out, int out_size, void* d_ws,
                              size_t ws_size, hipStream_t stream) {
  const float* gsim = (const float*)d_in[0];  // (128,128)
  const float* im = (const float*)d_in[1];    // (128,64,512)
  const float* s = (const float*)d_in[2];     // (128,32,512)
  const float* im_m = (const float*)d_in[3];  // (128,64)
  const float* s_m = (const float*)d_in[5];   // (128,32)
  float* out = (float*)d_out;

  float* ws = (float*)d_ws;
  float* nim = ws;                                         // 8192
  float* ns = ws + 8192;                                   // 4096
  float* i2t = ws + 12288;                                 // 16384
  float* t2i = ws + 28672;                                 // 16384
  float* grow = ws + 45056;                                // 128
  float* gcol = ws + 45184;                                // 128
  float* lrow = ws + 45312;                                // 128
  unsigned short* Gim = (unsigned short*)(ws + 45440);     // 128*64*64 bf16
  unsigned short* Gs = (unsigned short*)(ws + 307584);     // 128*32*32 bf16
  unsigned short* imn = (unsigned short*)(ws + 373120);    // 128*64*512 bf16
  unsigned short* sn = (unsigned short*)(ws + 2470272);    // 128*32*512 bf16

  gram_norm<<<dim3(256), dim3(256), 0, stream>>>(im, s, nim, ns, imn, sn, Gim, Gs);
  // i2t: ctx=images(LS=64,GC=2), qry=captions(LQ=32,GQ=4); 4 blocks/CU
  attn_tile<64, 32, 2, 4, 4><<<dim3(32, 64), dim3(256), 0, stream>>>(
      imn, sn, Gim, ns, im_m, i2t);
  // t2i: ctx=captions(LS=32,GC=4), qry=images(LQ=64,GQ=2); 3 blocks/CU
  attn_tile<32, 64, 4, 2, 3><<<dim3(64, 32), dim3(256), 0, stream>>>(
      sn, imn, Gs, nim, s_m, t2i);
  loss_rows<<<dim3(128), dim3(128), 0, stream>>>(gsim, i2t, t2i, grow, gcol, lrow);
  loss_final<<<dim3(1), dim3(128), 0, stream>>>(grow, gcol, lrow, out);
}